// Round 2
// baseline (1320.390 us; speedup 1.0000x reference)
//
#include <hip/hip_runtime.h>
#include <hip/hip_bf16.h>
#include <cstdint>
#include <cstddef>

#define S_LEN 4096
#define HIDDEN 2048
#define NHEADS 16
#define NKVH 2
#define HDIM 128

typedef __attribute__((ext_vector_type(8))) short short8;
typedef __attribute__((ext_vector_type(4))) short short4v;
typedef __attribute__((ext_vector_type(4))) float floatx4;
typedef __attribute__((ext_vector_type(4))) uint32_t uint4v;

__device__ __forceinline__ short f2bf(float f) {
  uint32_t u = __builtin_bit_cast(uint32_t, f);
  uint32_t r = (u + 0x7fffu + ((u >> 16) & 1u)) >> 16;
  return (short)(uint16_t)r;
}
__device__ __forceinline__ float bf2f(short s) {
  uint32_t u = ((uint32_t)(uint16_t)s) << 16;
  return __builtin_bit_cast(float, u);
}
__device__ __forceinline__ uint32_t pack_bf2(float lo, float hi) {
  return (uint32_t)(uint16_t)f2bf(lo) | ((uint32_t)(uint16_t)f2bf(hi) << 16);
}
// XOR-swizzled offset within a row of a row-major LDS tile; 16B chunks intact.
__device__ __forceinline__ int swz(int row, int ks, int mask) {
  int chunk = ks >> 3;
  return ((chunk ^ (row & mask)) << 3) | (ks & 7);
}

// ---------------- cast / pack kernel ----------------
__global__ void cast_kernel(const float* __restrict__ hs, const float* __restrict__ qw,
                            const float* __restrict__ kw, const float* __restrict__ vw,
                            const float* __restrict__ qb, const float* __restrict__ kb,
                            const float* __restrict__ vb, const float* __restrict__ ow,
                            short* __restrict__ hs_b, short* __restrict__ w_b,
                            short* __restrict__ ow_b, float* __restrict__ bias) {
  const int HS_N = S_LEN * HIDDEN;
  const int QW_N = NHEADS * HDIM * HIDDEN;
  const int KW_N = NKVH * HDIM * HIDDEN;
  const int OW_N = HIDDEN * HIDDEN;
  const int TOT = HS_N + QW_N + 2 * KW_N + OW_N + 2560;
  int idx = blockIdx.x * blockDim.x + threadIdx.x;
  int stride = gridDim.x * blockDim.x;
  for (int i = idx; i < TOT; i += stride) {
    int j = i;
    if (j < HS_N) { hs_b[j] = f2bf(hs[j]); continue; }
    j -= HS_N;
    if (j < QW_N) { w_b[j] = f2bf(qw[j]); continue; }
    j -= QW_N;
    if (j < KW_N) { w_b[QW_N + j] = f2bf(kw[j]); continue; }
    j -= KW_N;
    if (j < KW_N) { w_b[QW_N + KW_N + j] = f2bf(vw[j]); continue; }
    j -= KW_N;
    if (j < OW_N) { ow_b[j] = f2bf(ow[j]); continue; }
    j -= OW_N;
    if (j < 2048) { bias[j] = qb[j]; continue; }
    j -= 2048;
    if (j < 256) { bias[2048 + j] = kb[j]; continue; }
    j -= 256;
    bias[2304 + j] = vb[j];
  }
}

// ---------------- GEMM: C[M][N] = A[M][K] @ B[N][K]^T (+bias) ----------------
template<int N_COLS, bool BIAS, bool OUT_BF16>
__global__ __launch_bounds__(256, 2) void gemm_bt(const short* __restrict__ A,
                                                  const short* __restrict__ B,
                                                  const float* __restrict__ bias,
                                                  void* __restrict__ Cout, int K) {
  __shared__ __align__(16) short As[128 * 64];
  __shared__ __align__(16) short Bs[128 * 64];
  const int tid = threadIdx.x;
  const int lane = tid & 63;
  const int w = tid >> 6;
  const int wr = w >> 1, wc = w & 1;
  const int m0 = blockIdx.y * 128;
  const int n0 = blockIdx.x * 128;
  const int l15 = lane & 15, q = lane >> 4;

  floatx4 acc[4][4];
#pragma unroll
  for (int i = 0; i < 4; i++)
#pragma unroll
    for (int j = 0; j < 4; j++) acc[i][j] = (floatx4){0.f, 0.f, 0.f, 0.f};

  for (int k0 = 0; k0 < K; k0 += 64) {
#pragma unroll
    for (int r = 0; r < 4; r++) {
      int ci = r * 256 + tid;
      int row = ci >> 3, cc = (ci & 7) << 3;
      short8 av = *(const short8*)(A + (size_t)(m0 + row) * K + k0 + cc);
      *(short8*)(&As[row * 64 + swz(row, cc, 7)]) = av;
      short8 bv = *(const short8*)(B + (size_t)(n0 + row) * K + k0 + cc);
      *(short8*)(&Bs[row * 64 + swz(row, cc, 7)]) = bv;
    }
    __syncthreads();
#pragma unroll
    for (int ko = 0; ko < 2; ko++) {
      short8 a[4], b[4];
#pragma unroll
      for (int i = 0; i < 4; i++) {
        int m = wr * 64 + i * 16 + l15;
        a[i] = *(const short8*)(&As[m * 64 + swz(m, ko * 32 + q * 8, 7)]);
      }
#pragma unroll
      for (int j = 0; j < 4; j++) {
        int n = wc * 64 + j * 16 + l15;
        b[j] = *(const short8*)(&Bs[n * 64 + swz(n, ko * 32 + q * 8, 7)]);
      }
#pragma unroll
      for (int i = 0; i < 4; i++)
#pragma unroll
        for (int j = 0; j < 4; j++)
          acc[i][j] = __builtin_amdgcn_mfma_f32_16x16x32_bf16(a[i], b[j], acc[i][j], 0, 0, 0);
    }
    __syncthreads();
  }
#pragma unroll
  for (int i = 0; i < 4; i++)
#pragma unroll
    for (int j = 0; j < 4; j++) {
      int n = n0 + wc * 64 + j * 16 + l15;
      float bv = 0.f;
      if (BIAS) bv = bias[n];
#pragma unroll
      for (int r = 0; r < 4; r++) {
        int m = m0 + wr * 64 + i * 16 + q * 4 + r;
        float v = acc[i][j][r] + bv;
        if (OUT_BF16) ((short*)Cout)[(size_t)m * N_COLS + n] = f2bf(v);
        else          ((float*)Cout)[(size_t)m * N_COLS + n] = v;
      }
    }
}

// ---------------- RoPE + scatter ----------------
__global__ void rope_kernel(const short* __restrict__ qkv, short* __restrict__ Qr,
                            short* __restrict__ Kr, short* __restrict__ Vt) {
  const int s = blockIdx.x;
  const int tid = threadIdx.x;
  const short* row = qkv + (size_t)s * 2560;
  const float QSCALE = 0.08838834764831845f * 1.4426950408889634f; // 1/sqrt(128)*log2(e)
  const float L2T_64 = 19.931568569324174f / 64.0f;                 // log2(1e6)/64
  for (int p = tid; p < 1152; p += 256) {
    int h = p >> 6;
    int d = p & 63;
    int base = h * 128;
    float x1 = bf2f(row[base + d]);
    float x2 = bf2f(row[base + d + 64]);
    float invf = exp2f(-(float)d * L2T_64);
    float ang = (float)s * invf;
    float sn, cs;
    sincosf(ang, &sn, &cs);
    float o1 = x1 * cs - x2 * sn;
    float o2 = x2 * cs + x1 * sn;
    if (h < 16) {
      size_t o = ((size_t)h * S_LEN + s) * HDIM;
      Qr[o + d] = f2bf(o1 * QSCALE);
      Qr[o + d + 64] = f2bf(o2 * QSCALE);
    } else {
      size_t o = ((size_t)(h - 16) * S_LEN + s) * HDIM;
      Kr[o + d] = f2bf(o1);
      Kr[o + d + 64] = f2bf(o2);
    }
  }
  for (int p = tid; p < 256; p += 256) {
    int kv = p >> 7, d = p & 127;
    Vt[((size_t)kv * HDIM + d) * S_LEN + s] = row[2304 + p];
  }
}

// ---------------- attention pass 0: per-row (m, l) ----------------
// S^T orientation: per wave, B-operand = 32 query rows (2 n-tiles), A-operand = K
// straight from global. Per-lane online softmax state; quad merge at the end.
// No LDS, no barriers. Block = 2 waves = 64 query rows.
__global__ __launch_bounds__(128, 4) void attn_ml_kernel(
    const short* __restrict__ Qr, const short* __restrict__ Kr,
    float* __restrict__ ml) {
  const int bid = blockIdx.x;
  const int h = bid & 15;
  const int slot = bid >> 4;                               // 0..63
  const int qt = (slot & 1) ? (slot >> 1) : (63 - (slot >> 1)); // interleave big/small
  const int kv = h >> 3;
  const int tid = threadIdx.x;
  const int lane = tid & 63;
  const int w = tid >> 6;                                  // 0..1
  const int l15 = lane & 15, q = lane >> 4;
  const int qbase = qt * 64;
  const int row0 = qbase + w * 32;                         // wave rows [row0, row0+32)

  short8 bq[2][4];
#pragma unroll
  for (int n = 0; n < 2; n++)
#pragma unroll
    for (int ko = 0; ko < 4; ko++)
      bq[n][ko] = *(const short8*)(Qr + ((size_t)h * S_LEN + row0 + n * 16 + l15) * HDIM + ko * 32 + q * 8);

  const short* Kb = Kr + (size_t)kv * S_LEN * HDIM;
  float m_part[2] = {-1e30f, -1e30f};
  float l_part[2] = {0.f, 0.f};

  const int nsteps = qt + 1;
  for (int kt = 0; kt < nsteps; kt++) {
    const int j0 = kt * 64;
    floatx4 sacc[4][2];
#pragma unroll
    for (int mt = 0; mt < 4; mt++)
#pragma unroll
      for (int n = 0; n < 2; n++) sacc[mt][n] = (floatx4){0.f, 0.f, 0.f, 0.f};
#pragma unroll
    for (int ko = 0; ko < 4; ko++) {
      short8 ak[4];
#pragma unroll
      for (int mt = 0; mt < 4; mt++)
        ak[mt] = *(const short8*)(Kb + (size_t)(j0 + mt * 16 + l15) * HDIM + ko * 32 + q * 8);
#pragma unroll
      for (int mt = 0; mt < 4; mt++)
#pragma unroll
        for (int n = 0; n < 2; n++)
          sacc[mt][n] = __builtin_amdgcn_mfma_f32_16x16x32_bf16(ak[mt], bq[n][ko], sacc[mt][n], 0, 0, 0);
    }
    if (kt == nsteps - 1) {  // causal mask: only the last 64-key step straddles the diag
#pragma unroll
      for (int mt = 0; mt < 4; mt++)
#pragma unroll
        for (int n = 0; n < 2; n++)
#pragma unroll
          for (int r = 0; r < 4; r++) {
            int key = j0 + mt * 16 + q * 4 + r;
            int qr = row0 + n * 16 + l15;
            if (key > qr) sacc[mt][n][r] = -3.0e38f;
          }
    }
#pragma unroll
    for (int n = 0; n < 2; n++) {
      float mx = -3.0e38f;
#pragma unroll
      for (int mt = 0; mt < 4; mt++)
#pragma unroll
        for (int r = 0; r < 4; r++) mx = fmaxf(mx, sacc[mt][n][r]);
      float mnew = fmaxf(m_part[n], mx);
      float sum = 0.f;
#pragma unroll
      for (int mt = 0; mt < 4; mt++)
#pragma unroll
        for (int r = 0; r < 4; r++) sum += exp2f(sacc[mt][n][r] - mnew);
      l_part[n] = l_part[n] * exp2f(m_part[n] - mnew) + sum;
      m_part[n] = mnew;
    }
  }
  // merge partial (m,l) across the 4 quads holding the same query row
#pragma unroll
  for (int n = 0; n < 2; n++) {
    float m = m_part[n], l = l_part[n];
#pragma unroll
    for (int off = 16; off <= 32; off <<= 1) {
      float mo = __shfl_xor(m, off);
      float lo = __shfl_xor(l, off);
      float mn = fmaxf(m, mo);
      l = l * exp2f(m - mn) + lo * exp2f(mo - mn);
      m = mn;
    }
    if (q == 0) {
      int qr = row0 + n * 16 + l15;
      ml[h * S_LEN + qr] = m;
      ml[NHEADS * S_LEN + h * S_LEN + qr] = l;
    }
  }
}

// ---------------- attention pass 1: P, PV, colsum ----------------
// S^T QK (K LDS-staged, shared by 4 waves). P stays in registers: C-layout -> B-operand
// (P^T) via 16 quad-local shuffles; V direct from global as A-operand (O^T = Vt * P^T).
// colsum via 15-shuffle butterfly -> 1 atomicAdd per lane per step.
__global__ __launch_bounds__(256, 4) void attn_pv_kernel(
    const short* __restrict__ Qr, const short* __restrict__ Kr,
    const short* __restrict__ Vt, const float* __restrict__ ml,
    short* __restrict__ attn_out, float* __restrict__ acc_out) {
  __shared__ __align__(16) short Ks[64 * 128];   // 16 KB
  const int bid = blockIdx.x;
  const int h = bid & 15;
  const int slot = bid >> 4;
  const int qt = (slot & 1) ? (slot >> 1) : (63 - (slot >> 1));
  const int kv = h >> 3;
  const int tid = threadIdx.x;
  const int lane = tid & 63;
  const int w = tid >> 6;                        // 0..3
  const int l15 = lane & 15, q = lane >> 4;
  const int qbase = qt * 64;
  const int qrow = qbase + w * 16 + l15;         // this lane's query row

  short8 bq[4];
#pragma unroll
  for (int ko = 0; ko < 4; ko++)
    bq[ko] = *(const short8*)(Qr + ((size_t)h * S_LEN + qrow) * HDIM + ko * 32 + q * 8);

  const float m_lane = ml[h * S_LEN + qrow];
  const float linv = 1.0f / ml[NHEADS * S_LEN + h * S_LEN + qrow];

  floatx4 accO[8];
#pragma unroll
  for (int dt = 0; dt < 8; dt++) accO[dt] = (floatx4){0.f, 0.f, 0.f, 0.f};

  const short* Vb = Vt + (size_t)kv * HDIM * S_LEN;
  const int nsteps = qt + 1;
  for (int kt = 0; kt < nsteps; kt++) {
    const int j0 = kt * 64;
    __syncthreads();
#pragma unroll
    for (int r = 0; r < 4; r++) {                // stage K tile 64x128
      int ci = r * 256 + tid;
      int row = ci >> 4, cc = (ci & 15) << 3;
      short8 kvv = *(const short8*)(Kr + ((size_t)kv * S_LEN + j0 + row) * HDIM + cc);
      *(short8*)(&Ks[row * 128 + swz(row, cc, 15)]) = kvv;
    }
    __syncthreads();

    floatx4 sacc[4];
#pragma unroll
    for (int mt = 0; mt < 4; mt++) sacc[mt] = (floatx4){0.f, 0.f, 0.f, 0.f};
#pragma unroll
    for (int ko = 0; ko < 4; ko++) {
      short8 ak[4];
#pragma unroll
      for (int mt = 0; mt < 4; mt++) {
        int row = mt * 16 + l15;
        ak[mt] = *(const short8*)(&Ks[row * 128 + swz(row, ko * 32 + q * 8, 15)]);
      }
#pragma unroll
      for (int mt = 0; mt < 4; mt++)
        sacc[mt] = __builtin_amdgcn_mfma_f32_16x16x32_bf16(ak[mt], bq[ko], sacc[mt], 0, 0, 0);
    }

    float p[4][4];
    const bool boundary = (kt == nsteps - 1);
#pragma unroll
    for (int mt = 0; mt < 4; mt++)
#pragma unroll
      for (int r = 0; r < 4; r++) {
        float pv = exp2f(sacc[mt][r] - m_lane) * linv;
        if (boundary) {
          int key = j0 + mt * 16 + q * 4 + r;
          if (key > qrow) pv = 0.f;
        }
        p[mt][r] = pv;
      }

    // column sums over the 16 query rows (l15 lanes within each quad): butterfly
    {
      float v[16];
#pragma unroll
      for (int mt = 0; mt < 4; mt++)
#pragma unroll
        for (int r = 0; r < 4; r++) v[mt * 4 + r] = p[mt][r];
#pragma unroll
      for (int j = 0; j < 4; j++) {
        const int half = 8 >> j;
        const bool bit = (l15 >> j) & 1;
#pragma unroll
        for (int i = 0; i < 8; i++) {
          if (i < half) {
            float send = bit ? v[i] : v[i + half];
            float keep = bit ? v[i + half] : v[i];
            v[i] = keep + __shfl_xor(send, 1 << j);
          }
        }
      }
      int idx = ((l15 & 1) << 3) | ((l15 & 2) << 1) | ((l15 & 4) >> 1) | ((l15 & 8) >> 3);
      int key = j0 + (idx >> 2) * 16 + q * 4 + (idx & 3);
      atomicAdd(&acc_out[kv * S_LEN + key], v[0] * 0.125f);
    }

    // P (C-layout) -> B-operand fragments of P^T via quad-local shuffles, then PV
    uint32_t pk[4][2];
#pragma unroll
    for (int mt = 0; mt < 4; mt++) {
      pk[mt][0] = pack_bf2(p[mt][0], p[mt][1]);
      pk[mt][1] = pack_bf2(p[mt][2], p[mt][3]);
    }
#pragma unroll
    for (int ko2 = 0; ko2 < 2; ko2++) {
      uint32_t dw[4];
#pragma unroll
      for (int t = 0; t < 4; t++) {
        int qsrc = (2 * q + (t >> 1)) & 3;
        int src = qsrc * 16 + l15;
        uint32_t d0 = (uint32_t)__shfl((int)pk[2 * ko2][t & 1], src);
        uint32_t d1 = (uint32_t)__shfl((int)pk[2 * ko2 + 1][t & 1], src);
        dw[t] = (q >> 1) ? d1 : d0;
      }
      short8 bp = __builtin_bit_cast(short8, (uint4v){dw[0], dw[1], dw[2], dw[3]});
#pragma unroll
      for (int dh = 0; dh < 2; dh++) {
        short8 av[4];
#pragma unroll
        for (int dt = 0; dt < 4; dt++)
          av[dt] = *(const short8*)(Vb + (size_t)(dh * 64 + dt * 16 + l15) * S_LEN + j0 + ko2 * 32 + q * 8);
#pragma unroll
        for (int dt = 0; dt < 4; dt++)
          accO[dh * 4 + dt] = __builtin_amdgcn_mfma_f32_16x16x32_bf16(av[dt], bp, accO[dh * 4 + dt], 0, 0, 0);
      }
    }
  }

  // epilogue: O^T C-layout -> attn_out[qrow][h*128 + d], 8B packed stores
#pragma unroll
  for (int dt = 0; dt < 8; dt++) {
    short4v o;
#pragma unroll
    for (int r = 0; r < 4; r++) o[r] = f2bf(accO[dt][r]);
    *(short4v*)(attn_out + (size_t)qrow * HIDDEN + h * HDIM + dt * 16 + q * 4) = o;
  }
}

// ---------------- launch ----------------
extern "C" void kernel_launch(void* const* d_in, const int* in_sizes, int n_in,
                              void* d_out, int out_size, void* d_ws, size_t ws_size,
                              hipStream_t stream) {
  const float* hs = (const float*)d_in[0];
  const float* qw = (const float*)d_in[1];
  const float* qb = (const float*)d_in[2];
  const float* kw = (const float*)d_in[3];
  const float* kb = (const float*)d_in[4];
  const float* vw = (const float*)d_in[5];
  const float* vb = (const float*)d_in[6];
  const float* ow = (const float*)d_in[7];

  char* p = (char*)d_ws;
  auto alloc = [&](size_t bytes) { char* r = p; p += (bytes + 255) & ~(size_t)255; return r; };
  short* hs_b   = (short*)alloc((size_t)S_LEN * HIDDEN * 2);
  short* w_b    = (short*)alloc((size_t)2560 * HIDDEN * 2);
  short* ow_b   = (short*)alloc((size_t)HIDDEN * HIDDEN * 2);
  float* bias   = (float*)alloc(2560 * 4);
  short* qkv_t  = (short*)alloc((size_t)S_LEN * 2560 * 2);
  short* Qr     = (short*)alloc((size_t)NHEADS * S_LEN * HDIM * 2);
  short* Kr     = (short*)alloc((size_t)NKVH * S_LEN * HDIM * 2);
  short* Vt     = (short*)alloc((size_t)NKVH * HDIM * S_LEN * 2);
  float* ml     = (float*)alloc((size_t)2 * NHEADS * S_LEN * 4);
  short* attn_b = (short*)alloc((size_t)S_LEN * HIDDEN * 2);

  float* out = (float*)d_out;
  float* acc_out = out + (size_t)S_LEN * HIDDEN;

  hipMemsetAsync(acc_out, 0, (size_t)NKVH * S_LEN * sizeof(float), stream);
  cast_kernel<<<4096, 256, 0, stream>>>(hs, qw, kw, vw, qb, kb, vb, ow, hs_b, w_b, ow_b, bias);
  gemm_bt<2560, true, true><<<dim3(20, 32), 256, 0, stream>>>(hs_b, w_b, bias, qkv_t, HIDDEN);
  rope_kernel<<<S_LEN, 256, 0, stream>>>(qkv_t, Qr, Kr, Vt);
  attn_ml_kernel<<<1024, 128, 0, stream>>>(Qr, Kr, ml);
  attn_pv_kernel<<<1024, 256, 0, stream>>>(Qr, Kr, Vt, ml, attn_b, acc_out);
  gemm_bt<2048, false, false><<<dim3(16, 32), 256, 0, stream>>>(attn_b, ow_b, nullptr, out, HIDDEN);
}

// Round 3
// 686.394 us; speedup vs baseline: 1.9237x; 1.9237x over previous
//
#include <hip/hip_runtime.h>
#include <hip/hip_bf16.h>
#include <cstdint>
#include <cstddef>

#define S_LEN 4096
#define HIDDEN 2048
#define NHEADS 16
#define NKVH 2
#define HDIM 128

typedef __attribute__((ext_vector_type(8))) short short8;
typedef __attribute__((ext_vector_type(4))) short short4v;
typedef __attribute__((ext_vector_type(4))) float floatx4;

__device__ __forceinline__ short f2bf(float f) {
  uint32_t u = __builtin_bit_cast(uint32_t, f);
  uint32_t r = (u + 0x7fffu + ((u >> 16) & 1u)) >> 16;
  return (short)(uint16_t)r;
}
__device__ __forceinline__ float bf2f(short s) {
  uint32_t u = ((uint32_t)(uint16_t)s) << 16;
  return __builtin_bit_cast(float, u);
}
// XOR-swizzled element offset within a row of a row-major LDS tile; 16B chunks intact.
__device__ __forceinline__ int swz(int row, int ks, int mask) {
  int chunk = ks >> 3;
  return ((chunk ^ (row & mask)) << 3) | (ks & 7);
}

// ---------------- cast / pack kernel (float4 -> bf16x4) ----------------
__device__ __forceinline__ void cvt4(const float* __restrict__ src, short* __restrict__ dst, int qi) {
  float4 v = ((const float4*)src)[qi];
  short4v o = { f2bf(v.x), f2bf(v.y), f2bf(v.z), f2bf(v.w) };
  ((short4v*)dst)[qi] = o;
}
__global__ void cast_kernel(const float* __restrict__ hs, const float* __restrict__ qw,
                            const float* __restrict__ kw, const float* __restrict__ vw,
                            const float* __restrict__ qb, const float* __restrict__ kb,
                            const float* __restrict__ vb, const float* __restrict__ ow,
                            short* __restrict__ hs_b, short* __restrict__ w_b,
                            short* __restrict__ ow_b, float* __restrict__ bias) {
  const int HS_Q = S_LEN * HIDDEN / 4;
  const int QW_Q = NHEADS * HDIM * HIDDEN / 4;
  const int KW_Q = NKVH * HDIM * HIDDEN / 4;
  const int OW_Q = HIDDEN * HIDDEN / 4;
  const int TOTQ = HS_Q + QW_Q + 2 * KW_Q + OW_Q + 640;
  int idx = blockIdx.x * blockDim.x + threadIdx.x;
  int stride = gridDim.x * blockDim.x;
  for (int i = idx; i < TOTQ; i += stride) {
    int j = i;
    if (j < HS_Q) { cvt4(hs, hs_b, j); continue; }
    j -= HS_Q;
    if (j < QW_Q) { cvt4(qw, w_b, j); continue; }
    j -= QW_Q;
    if (j < KW_Q) { cvt4(kw, w_b + NHEADS * HDIM * HIDDEN, j); continue; }
    j -= KW_Q;
    if (j < KW_Q) { cvt4(vw, w_b + (NHEADS + NKVH) * HDIM * HIDDEN, j); continue; }
    j -= KW_Q;
    if (j < OW_Q) { cvt4(ow, ow_b, j); continue; }
    j -= OW_Q;
    if (j < 512) { ((float4*)bias)[j] = ((const float4*)qb)[j]; continue; }
    j -= 512;
    if (j < 64) { ((float4*)(bias + 2048))[j] = ((const float4*)kb)[j]; continue; }
    j -= 64;
    ((float4*)(bias + 2304))[j] = ((const float4*)vb)[j];
  }
}

// ---------------- GEMM: C[M][N] = A[M][K] @ B[N][K]^T (+bias) ----------------
template<int N_COLS, bool BIAS, bool OUT_BF16>
__global__ __launch_bounds__(256, 2) void gemm_bt(const short* __restrict__ A,
                                                  const short* __restrict__ B,
                                                  const float* __restrict__ bias,
                                                  void* __restrict__ Cout, int K) {
  __shared__ __align__(16) short As[128 * 64];
  __shared__ __align__(16) short Bs[128 * 64];
  const int tid = threadIdx.x;
  const int lane = tid & 63;
  const int w = tid >> 6;
  const int wr = w >> 1, wc = w & 1;
  const int m0 = blockIdx.y * 128;
  const int n0 = blockIdx.x * 128;
  const int l15 = lane & 15, q = lane >> 4;

  floatx4 acc[4][4];
#pragma unroll
  for (int i = 0; i < 4; i++)
#pragma unroll
    for (int j = 0; j < 4; j++) acc[i][j] = (floatx4){0.f, 0.f, 0.f, 0.f};

  for (int k0 = 0; k0 < K; k0 += 64) {
#pragma unroll
    for (int r = 0; r < 4; r++) {
      int ci = r * 256 + tid;
      int row = ci >> 3, cc = (ci & 7) << 3;
      short8 av = *(const short8*)(A + (size_t)(m0 + row) * K + k0 + cc);
      *(short8*)(&As[row * 64 + swz(row, cc, 7)]) = av;
      short8 bv = *(const short8*)(B + (size_t)(n0 + row) * K + k0 + cc);
      *(short8*)(&Bs[row * 64 + swz(row, cc, 7)]) = bv;
    }
    __syncthreads();
#pragma unroll
    for (int ko = 0; ko < 2; ko++) {
      short8 a[4], b[4];
#pragma unroll
      for (int i = 0; i < 4; i++) {
        int m = wr * 64 + i * 16 + l15;
        a[i] = *(const short8*)(&As[m * 64 + swz(m, ko * 32 + q * 8, 7)]);
      }
#pragma unroll
      for (int j = 0; j < 4; j++) {
        int n = wc * 64 + j * 16 + l15;
        b[j] = *(const short8*)(&Bs[n * 64 + swz(n, ko * 32 + q * 8, 7)]);
      }
#pragma unroll
      for (int i = 0; i < 4; i++)
#pragma unroll
        for (int j = 0; j < 4; j++)
          acc[i][j] = __builtin_amdgcn_mfma_f32_16x16x32_bf16(a[i], b[j], acc[i][j], 0, 0, 0);
    }
    __syncthreads();
  }
#pragma unroll
  for (int i = 0; i < 4; i++)
#pragma unroll
    for (int j = 0; j < 4; j++) {
      int n = n0 + wc * 64 + j * 16 + l15;
      float bv = 0.f;
      if (BIAS) bv = bias[n];
#pragma unroll
      for (int r = 0; r < 4; r++) {
        int m = m0 + wr * 64 + i * 16 + q * 4 + r;
        float v = acc[i][j][r] + bv;
        if (OUT_BF16) ((short*)Cout)[(size_t)m * N_COLS + n] = f2bf(v);
        else          ((float*)Cout)[(size_t)m * N_COLS + n] = v;
      }
    }
}

// ---------------- RoPE + scatter ----------------
__global__ void rope_kernel(const short* __restrict__ qkv, short* __restrict__ Qr,
                            short* __restrict__ Kr, short* __restrict__ Vt) {
  const int s = blockIdx.x;
  const int tid = threadIdx.x;
  const short* row = qkv + (size_t)s * 2560;
  const float QSCALE = 0.08838834764831845f * 1.4426950408889634f; // 1/sqrt(128)*log2(e)
  const float L2T_64 = 19.931568569324174f / 64.0f;                 // log2(1e6)/64
  for (int p = tid; p < 1152; p += 256) {
    int h = p >> 6;
    int d = p & 63;
    int base = h * 128;
    float x1 = bf2f(row[base + d]);
    float x2 = bf2f(row[base + d + 64]);
    float invf = exp2f(-(float)d * L2T_64);
    float ang = (float)s * invf;
    float sn, cs;
    sincosf(ang, &sn, &cs);
    float o1 = x1 * cs - x2 * sn;
    float o2 = x2 * cs + x1 * sn;
    if (h < 16) {
      size_t o = ((size_t)h * S_LEN + s) * HDIM;
      Qr[o + d] = f2bf(o1 * QSCALE);
      Qr[o + d + 64] = f2bf(o2 * QSCALE);
    } else {
      size_t o = ((size_t)(h - 16) * S_LEN + s) * HDIM;
      Kr[o + d] = f2bf(o1);
      Kr[o + d + 64] = f2bf(o2);
    }
  }
  for (int p = tid; p < 256; p += 256) {
    int kv = p >> 7, d = p & 127;
    Vt[((size_t)kv * HDIM + d) * S_LEN + s] = row[2304 + p];
  }
}

// ---------------- fused attention: sweep A (rowsums) + sweep B (P, PV, colsum) ----------------
// Fixed-base softmax (logits are O(1) here; no overflow without max subtraction):
//   L_i = log2(sum_j exp2(s_ij));  p_ij = exp2(s_ij - L_i)  (Q pre-scaled into exp2 domain).
// Sweep A: S^T = K·Q^T -> lane column i=l15 -> per-lane scalar lsum, no per-step shuffles.
// Sweep B: S = Q·K^T -> colsum over i is cheap (3 adds + 2 shfl per jt); P via wave-private
// LDS round-trip to A-operand layout; V LDS-staged; -L folded into MFMA C-init.
// Colsum partials -> part[h][qt][j] via plain coalesced stores (no global atomics).
__global__ __launch_bounds__(256, 3) void attn_kernel(
    const short* __restrict__ Qr, const short* __restrict__ Kr,
    const short* __restrict__ Vt, short* __restrict__ attn_out,
    float* __restrict__ part) {
  __shared__ __align__(16) short Ks[64 * 128];     // 16 KB [j][d] swz mask 15
  __shared__ __align__(16) short Vs[128 * 64];     // 16 KB [d][j] swz mask 7
  __shared__ __align__(16) short Ps[4][16 * 64];   //  8 KB per-wave [i][j] swz mask 7
  __shared__ float cbuf[2][4][64];                 //  2 KB colsum staging (dbuf)

  const int bid = blockIdx.x;
  const int h = bid & 15;
  const int slot = bid >> 4;
  const int qt = (slot & 1) ? (slot >> 1) : (63 - (slot >> 1)); // interleave big/small
  const int kv = h >> 3;
  const int tid = threadIdx.x;
  const int lane = tid & 63;
  const int w = tid >> 6;
  const int l15 = lane & 15, q = lane >> 4;
  const int qbase = qt * 64;
  const int iFrag = qbase + w * 16 + l15;   // i of this lane's Q fragment (operand 16-dim)

  short8 fq[4];                              // dual-use A/B operand (same lane map)
#pragma unroll
  for (int ko = 0; ko < 4; ko++)
    fq[ko] = *(const short8*)(Qr + ((size_t)h * S_LEN + iFrag) * HDIM + ko * 32 + q * 8);

  const short* Kb = Kr + (size_t)kv * S_LEN * HDIM;
  const short* Vb = Vt + (size_t)kv * HDIM * S_LEN;
  const int nsteps = qt + 1;

  // ---------- sweep A: l_i ----------
  float lsum = 0.f;
  for (int kt = 0; kt < nsteps; kt++) {
    const int j0 = kt * 64;
    __syncthreads();
#pragma unroll
    for (int r = 0; r < 4; r++) {
      int ci = r * 256 + tid;
      int row = ci >> 4, cc = (ci & 15) << 3;
      *(short8*)(&Ks[row * 128 + swz(row, cc, 15)]) =
          *(const short8*)(Kb + (size_t)(j0 + row) * HDIM + cc);
    }
    __syncthreads();
    floatx4 sacc[4];
#pragma unroll
    for (int mt = 0; mt < 4; mt++) sacc[mt] = (floatx4){0.f, 0.f, 0.f, 0.f};
#pragma unroll
    for (int ko = 0; ko < 4; ko++) {
      short8 ak[4];
#pragma unroll
      for (int mt = 0; mt < 4; mt++) {
        int row = mt * 16 + l15;
        ak[mt] = *(const short8*)(&Ks[row * 128 + swz(row, ko * 32 + q * 8, 15)]);
      }
#pragma unroll
      for (int mt = 0; mt < 4; mt++)
        sacc[mt] = __builtin_amdgcn_mfma_f32_16x16x32_bf16(ak[mt], fq[ko], sacc[mt], 0, 0, 0);
    }
    if (kt == nsteps - 1) {   // causal: mask j > i (i = iFrag, the C-layout column)
#pragma unroll
      for (int mt = 0; mt < 4; mt++)
#pragma unroll
        for (int r = 0; r < 4; r++)
          if (j0 + mt * 16 + q * 4 + r > iFrag) sacc[mt][r] = -3.0e38f;
    }
#pragma unroll
    for (int mt = 0; mt < 4; mt++)
#pragma unroll
      for (int r = 0; r < 4; r++) lsum += exp2f(sacc[mt][r]);
  }
  lsum += __shfl_xor(lsum, 16);
  lsum += __shfl_xor(lsum, 32);
  const float L = log2f(lsum);              // per lane, for row i = iFrag (l15-mapped)
  // redistribute: sweep B rows are i_local = q*4+r -> fetch L from lane (q*4+r)
  floatx4 negL;
#pragma unroll
  for (int r = 0; r < 4; r++) negL[r] = -__shfl(L, q * 4 + r);

  // ---------- sweep B: P, PV, colsum ----------
  floatx4 accO[8];
#pragma unroll
  for (int dt = 0; dt < 8; dt++) accO[dt] = (floatx4){0.f, 0.f, 0.f, 0.f};

  for (int kt = 0; kt < nsteps; kt++) {
    const int j0 = kt * 64;
    __syncthreads();
#pragma unroll
    for (int r = 0; r < 4; r++) {
      int ci = r * 256 + tid;
      int row = ci >> 4, cc = (ci & 15) << 3;
      *(short8*)(&Ks[row * 128 + swz(row, cc, 15)]) =
          *(const short8*)(Kb + (size_t)(j0 + row) * HDIM + cc);
      int vr = ci >> 3, vc = (ci & 7) << 3;
      *(short8*)(&Vs[vr * 64 + swz(vr, vc, 7)]) =
          *(const short8*)(Vb + (size_t)vr * S_LEN + j0 + vc);
    }
    __syncthreads();
    // flush previous step's colsum (cbuf[(kt-1)&1] is complete and stable here)
    if (kt > 0 && tid < 64) {
      int pb = (kt - 1) & 1;
      float s = cbuf[pb][0][tid] + cbuf[pb][1][tid] + cbuf[pb][2][tid] + cbuf[pb][3][tid];
      part[((size_t)(h * 64 + qt)) * 4096 + (size_t)(kt - 1) * 64 + tid] = s;
    }

    floatx4 sacc[4];
#pragma unroll
    for (int jt = 0; jt < 4; jt++) sacc[jt] = negL;   // -L folded into C init
#pragma unroll
    for (int ko = 0; ko < 4; ko++) {
      short8 bk[4];
#pragma unroll
      for (int jt = 0; jt < 4; jt++) {
        int row = jt * 16 + l15;
        bk[jt] = *(const short8*)(&Ks[row * 128 + swz(row, ko * 32 + q * 8, 15)]);
      }
#pragma unroll
      for (int jt = 0; jt < 4; jt++)
        sacc[jt] = __builtin_amdgcn_mfma_f32_16x16x32_bf16(fq[ko], bk[jt], sacc[jt], 0, 0, 0);
    }

    const bool bnd = (kt == nsteps - 1);
    short* myP = &Ps[w][0];
#pragma unroll
    for (int jt = 0; jt < 4; jt++) {
      float csum = 0.f;
#pragma unroll
      for (int r = 0; r < 4; r++) {
        float p = exp2f(sacc[jt][r]);
        if (bnd && (j0 + jt * 16 + l15 > qbase + w * 16 + q * 4 + r)) p = 0.f;
        csum += p;
        int pr = q * 4 + r;
        myP[pr * 64 + swz(pr, jt * 16 + l15, 7)] = f2bf(p);
      }
      csum += __shfl_xor(csum, 16);
      csum += __shfl_xor(csum, 32);
      if (q == 0) cbuf[kt & 1][w][jt * 16 + l15] = csum;
    }

#pragma unroll
    for (int ko2 = 0; ko2 < 2; ko2++) {
      short8 ap = *(const short8*)(&myP[l15 * 64 + swz(l15, ko2 * 32 + q * 8, 7)]);
#pragma unroll
      for (int dt = 0; dt < 8; dt++) {
        int vrow = dt * 16 + l15;
        short8 bv = *(const short8*)(&Vs[vrow * 64 + swz(vrow, ko2 * 32 + q * 8, 7)]);
        accO[dt] = __builtin_amdgcn_mfma_f32_16x16x32_bf16(ap, bv, accO[dt], 0, 0, 0);
      }
    }
  }

  __syncthreads();
  if (tid < 64) {   // flush last step's colsum
    int pb = (nsteps - 1) & 1;
    float s = cbuf[pb][0][tid] + cbuf[pb][1][tid] + cbuf[pb][2][tid] + cbuf[pb][3][tid];
    part[((size_t)(h * 64 + qt)) * 4096 + (size_t)(nsteps - 1) * 64 + tid] = s;
  }
#pragma unroll
  for (int dt = 0; dt < 8; dt++)
#pragma unroll
    for (int r = 0; r < 4; r++) {
      int i = qbase + w * 16 + q * 4 + r;
      attn_out[(size_t)i * HIDDEN + h * HDIM + dt * 16 + l15] = f2bf(accO[dt][r]);
    }
}

// ---------------- colsum reduction: part -> acc_out ----------------
__global__ void reduce_acc(const float* __restrict__ part, float* __restrict__ acc) {
  int j = blockIdx.x * 256 + threadIdx.x;   // 0..8191
  int hy = blockIdx.y;                      // 0..7
  int kvg = j >> 12, jj = j & 4095;
  int hh = kvg * 8 + hy;
  float s = 0.f;
  for (int qt = jj >> 6; qt < 64; qt++)
    s += part[((size_t)(hh * 64 + qt)) * 4096 + jj];
  atomicAdd(&acc[j], s * 0.125f);
}

// ---------------- launch ----------------
extern "C" void kernel_launch(void* const* d_in, const int* in_sizes, int n_in,
                              void* d_out, int out_size, void* d_ws, size_t ws_size,
                              hipStream_t stream) {
  const float* hs = (const float*)d_in[0];
  const float* qw = (const float*)d_in[1];
  const float* qb = (const float*)d_in[2];
  const float* kw = (const float*)d_in[3];
  const float* kb = (const float*)d_in[4];
  const float* vw = (const float*)d_in[5];
  const float* vb = (const float*)d_in[6];
  const float* ow = (const float*)d_in[7];

  char* p = (char*)d_ws;
  auto alloc = [&](size_t bytes) { char* r = p; p += (bytes + 255) & ~(size_t)255; return r; };
  short* hs_b   = (short*)alloc((size_t)S_LEN * HIDDEN * 2);
  short* w_b    = (short*)alloc((size_t)2560 * HIDDEN * 2);
  short* ow_b   = (short*)alloc((size_t)HIDDEN * HIDDEN * 2);
  float* bias   = (float*)alloc(2560 * 4);
  short* qkv_t  = (short*)alloc((size_t)S_LEN * 2560 * 2);
  short* Qr     = (short*)alloc((size_t)NHEADS * S_LEN * HDIM * 2);
  short* Kr     = (short*)alloc((size_t)NKVH * S_LEN * HDIM * 2);
  short* Vt     = (short*)alloc((size_t)NKVH * HDIM * S_LEN * 2);
  short* attn_b = (short*)alloc((size_t)S_LEN * HIDDEN * 2);
  float* part   = (float*)alloc((size_t)NHEADS * 64 * 4096 * 4);

  float* out = (float*)d_out;
  float* acc_out = out + (size_t)S_LEN * HIDDEN;

  hipMemsetAsync(acc_out, 0, (size_t)NKVH * S_LEN * sizeof(float), stream);
  cast_kernel<<<4096, 256, 0, stream>>>(hs, qw, kw, vw, qb, kb, vb, ow, hs_b, w_b, ow_b, bias);
  gemm_bt<2560, true, true><<<dim3(20, 32), 256, 0, stream>>>(hs_b, w_b, bias, qkv_t, HIDDEN);
  rope_kernel<<<S_LEN, 256, 0, stream>>>(qkv_t, Qr, Kr, Vt);
  attn_kernel<<<1024, 256, 0, stream>>>(Qr, Kr, Vt, attn_b, part);
  reduce_acc<<<dim3(32, 8), 256, 0, stream>>>(part, acc_out);
  gemm_bt<2048, false, false><<<dim3(16, 32), 256, 0, stream>>>(attn_b, ow_b, nullptr, out, HIDDEN);
}

// Round 5
// 568.869 us; speedup vs baseline: 2.3211x; 1.2066x over previous
//
#include <hip/hip_runtime.h>
#include <hip/hip_bf16.h>
#include <cstdint>
#include <cstddef>

#define S_LEN 4096
#define HIDDEN 2048
#define NHEADS 16
#define NKVH 2
#define HDIM 128

typedef __attribute__((ext_vector_type(8))) short short8;
typedef __attribute__((ext_vector_type(4))) short short4v;
typedef __attribute__((ext_vector_type(4))) float floatx4;
typedef __attribute__((ext_vector_type(16))) float floatx16;

__device__ __forceinline__ short f2bf(float f) {
  uint32_t u = __builtin_bit_cast(uint32_t, f);
  uint32_t r = (u + 0x7fffu + ((u >> 16) & 1u)) >> 16;
  return (short)(uint16_t)r;
}
__device__ __forceinline__ float bf2f(short s) {
  uint32_t u = ((uint32_t)(uint16_t)s) << 16;
  return __builtin_bit_cast(float, u);
}
// XOR-swizzled element offset within a row of a row-major LDS tile; 16B chunks intact.
__device__ __forceinline__ int swz(int row, int ks, int mask) {
  int chunk = ks >> 3;
  return ((chunk ^ (row & mask)) << 3) | (ks & 7);
}
// 16B LDS read/write as 2x b64 (for odd-stride layouts that break b128 alignment)
__device__ __forceinline__ short8 lds_read8(const short* p) {
  short4v a = *(const short4v*)p;
  short4v b = *(const short4v*)(p + 4);
  short8 r;
  r[0] = a[0]; r[1] = a[1]; r[2] = a[2]; r[3] = a[3];
  r[4] = b[0]; r[5] = b[1]; r[6] = b[2]; r[7] = b[3];
  return r;
}
__device__ __forceinline__ void lds_write8(short* p, short8 v) {
  *(short4v*)p = (short4v){v[0], v[1], v[2], v[3]};
  *(short4v*)(p + 4) = (short4v){v[4], v[5], v[6], v[7]};
}

// ---------------- cast / pack kernel (float4 -> bf16x4) ----------------
__device__ __forceinline__ void cvt4(const float* __restrict__ src, short* __restrict__ dst, int qi) {
  float4 v = ((const float4*)src)[qi];
  short4v o = { f2bf(v.x), f2bf(v.y), f2bf(v.z), f2bf(v.w) };
  ((short4v*)dst)[qi] = o;
}
__global__ void cast_kernel(const float* __restrict__ hs, const float* __restrict__ qw,
                            const float* __restrict__ kw, const float* __restrict__ vw,
                            const float* __restrict__ qb, const float* __restrict__ kb,
                            const float* __restrict__ vb, const float* __restrict__ ow,
                            short* __restrict__ hs_b, short* __restrict__ w_b,
                            short* __restrict__ ow_b, float* __restrict__ bias) {
  const int HS_Q = S_LEN * HIDDEN / 4;
  const int QW_Q = NHEADS * HDIM * HIDDEN / 4;
  const int KW_Q = NKVH * HDIM * HIDDEN / 4;
  const int OW_Q = HIDDEN * HIDDEN / 4;
  const int TOTQ = HS_Q + QW_Q + 2 * KW_Q + OW_Q + 640;
  int idx = blockIdx.x * blockDim.x + threadIdx.x;
  int stride = gridDim.x * blockDim.x;
  for (int i = idx; i < TOTQ; i += stride) {
    int j = i;
    if (j < HS_Q) { cvt4(hs, hs_b, j); continue; }
    j -= HS_Q;
    if (j < QW_Q) { cvt4(qw, w_b, j); continue; }
    j -= QW_Q;
    if (j < KW_Q) { cvt4(kw, w_b + NHEADS * HDIM * HIDDEN, j); continue; }
    j -= KW_Q;
    if (j < KW_Q) { cvt4(vw, w_b + (NHEADS + NKVH) * HDIM * HIDDEN, j); continue; }
    j -= KW_Q;
    if (j < OW_Q) { cvt4(ow, ow_b, j); continue; }
    j -= OW_Q;
    if (j < 512) { ((float4*)bias)[j] = ((const float4*)qb)[j]; continue; }
    j -= 512;
    if (j < 64) { ((float4*)(bias + 2048))[j] = ((const float4*)kb)[j]; continue; }
    j -= 64;
    ((float4*)(bias + 2304))[j] = ((const float4*)vb)[j];
  }
}

// ---------------- GEMM: C[M][N] = A[M][K] @ B[N][K]^T (+bias) ----------------
template<int N_COLS, bool BIAS, bool OUT_BF16>
__global__ __launch_bounds__(256, 2) void gemm_bt(const short* __restrict__ A,
                                                  const short* __restrict__ B,
                                                  const float* __restrict__ bias,
                                                  void* __restrict__ Cout, int K) {
  __shared__ __align__(16) short As[128 * 64];
  __shared__ __align__(16) short Bs[128 * 64];
  const int tid = threadIdx.x;
  const int lane = tid & 63;
  const int w = tid >> 6;
  const int wr = w >> 1, wc = w & 1;
  const int m0 = blockIdx.y * 128;
  const int n0 = blockIdx.x * 128;
  const int l15 = lane & 15, q = lane >> 4;

  floatx4 acc[4][4];
#pragma unroll
  for (int i = 0; i < 4; i++)
#pragma unroll
    for (int j = 0; j < 4; j++) acc[i][j] = (floatx4){0.f, 0.f, 0.f, 0.f};

  for (int k0 = 0; k0 < K; k0 += 64) {
#pragma unroll
    for (int r = 0; r < 4; r++) {
      int ci = r * 256 + tid;
      int row = ci >> 3, cc = (ci & 7) << 3;
      short8 av = *(const short8*)(A + (size_t)(m0 + row) * K + k0 + cc);
      *(short8*)(&As[row * 64 + swz(row, cc, 7)]) = av;
      short8 bv = *(const short8*)(B + (size_t)(n0 + row) * K + k0 + cc);
      *(short8*)(&Bs[row * 64 + swz(row, cc, 7)]) = bv;
    }
    __syncthreads();
#pragma unroll
    for (int ko = 0; ko < 2; ko++) {
      short8 a[4], b[4];
#pragma unroll
      for (int i = 0; i < 4; i++) {
        int m = wr * 64 + i * 16 + l15;
        a[i] = *(const short8*)(&As[m * 64 + swz(m, ko * 32 + q * 8, 7)]);
      }
#pragma unroll
      for (int j = 0; j < 4; j++) {
        int n = wc * 64 + j * 16 + l15;
        b[j] = *(const short8*)(&Bs[n * 64 + swz(n, ko * 32 + q * 8, 7)]);
      }
#pragma unroll
      for (int i = 0; i < 4; i++)
#pragma unroll
        for (int j = 0; j < 4; j++)
          acc[i][j] = __builtin_amdgcn_mfma_f32_16x16x32_bf16(a[i], b[j], acc[i][j], 0, 0, 0);
    }
    __syncthreads();
  }
#pragma unroll
  for (int i = 0; i < 4; i++)
#pragma unroll
    for (int j = 0; j < 4; j++) {
      int n = n0 + wc * 64 + j * 16 + l15;
      float bv = 0.f;
      if (BIAS) bv = bias[n];
#pragma unroll
      for (int r = 0; r < 4; r++) {
        int m = m0 + wr * 64 + i * 16 + q * 4 + r;
        float v = acc[i][j][r] + bv;
        if (OUT_BF16) ((short*)Cout)[(size_t)m * N_COLS + n] = f2bf(v);
        else          ((float*)Cout)[(size_t)m * N_COLS + n] = v;
      }
    }
}

// ---------------- RoPE + scatter ----------------
__global__ void rope_kernel(const short* __restrict__ qkv, short* __restrict__ Qr,
                            short* __restrict__ Kr, short* __restrict__ Vt) {
  const int s = blockIdx.x;
  const int tid = threadIdx.x;
  const short* row = qkv + (size_t)s * 2560;
  const float QSCALE = 0.08838834764831845f * 1.4426950408889634f; // 1/sqrt(128)*log2(e)
  const float L2T_64 = 19.931568569324174f / 64.0f;                 // log2(1e6)/64
  for (int p = tid; p < 1152; p += 256) {
    int h = p >> 6;
    int d = p & 63;
    int base = h * 128;
    float x1 = bf2f(row[base + d]);
    float x2 = bf2f(row[base + d + 64]);
    float invf = exp2f(-(float)d * L2T_64);
    float ang = (float)s * invf;
    float sn, cs;
    sincosf(ang, &sn, &cs);
    float o1 = x1 * cs - x2 * sn;
    float o2 = x2 * cs + x1 * sn;
    if (h < 16) {
      size_t o = ((size_t)h * S_LEN + s) * HDIM;
      Qr[o + d] = f2bf(o1 * QSCALE);
      Qr[o + d + 64] = f2bf(o2 * QSCALE);
    } else {
      size_t o = ((size_t)(h - 16) * S_LEN + s) * HDIM;
      Kr[o + d] = f2bf(o1);
      Kr[o + d + 64] = f2bf(o2);
    }
  }
  for (int p = tid; p < 256; p += 256) {
    int kv = p >> 7, d = p & 127;
    Vt[((size_t)kv * HDIM + d) * S_LEN + s] = row[2304 + p];
  }
}

// Shared helpers for the 32x32x16 attention kernels.
// C/D layout (verified, matches AMD matrix calculator): col(n) = lane&31,
// row(m) = (reg&3) + 8*(reg>>2) + 4*(lane>>5).
// A/B operand: m/n = lane&31, k = (lane>>5)*8 + idx.
#define KS_STRIDE 132   // odd dword stride -> 2-way max on frag reads, 2xb64 access
#define VS_STRIDE 68
#define PS_STRIDE 68

// Manual LDS arena offsets for attn_pv (shorts). Single object => the epilogue
// overlay (Es spans Ks+Vs) is well-defined, provably disjoint from Ps/cbuf.
#define AR_KS   0                    // 64*132  = 8448 shorts
#define AR_VS   8448                 // 128*68  = 8704 shorts
#define AR_PS   17152                // 4*32*68 = 8704 shorts
#define AR_CB   25856                // cbuf: 2*4*64 floats = 1024 shorts
#define AR_TOT  26880                // 53760 bytes
// Es span (epilogue): 3*4224 + 31*132 + 127 = 16891 < AR_PS  -> safe overlay.

// ---------------- sweep A: row sums L_i = log2(sum_j exp2(s_ij)) ----------------
// S^T = K·Q^T: per wave 64 j x 32 i per step; lane owns column i -> scalar lsum.
__global__ __launch_bounds__(256, 4) void attn_l_kernel(
    const short* __restrict__ Qr, const short* __restrict__ Kr,
    float* __restrict__ Lg) {
  __shared__ __align__(16) short Ks[64 * KS_STRIDE];   // 16.5 KB [j][d]

  const int bid = blockIdx.x;
  const int h = bid & 15;
  const int slot = bid >> 4;                                   // 0..31
  const int qt = (slot & 1) ? (slot >> 1) : (31 - (slot >> 1)); // interleave big/small
  const int kv = h >> 3;
  const int tid = threadIdx.x;
  const int lane = tid & 63;
  const int w = tid >> 6;
  const int l31 = lane & 31, hf = lane >> 5;
  const int i0 = qt * 128;
  const int iCol = i0 + w * 32 + l31;   // this lane's query column

  short8 fq[8];
#pragma unroll
  for (int kc = 0; kc < 8; kc++)
    fq[kc] = *(const short8*)(Qr + ((size_t)h * S_LEN + iCol) * HDIM + kc * 16 + hf * 8);

  const short* Kb = Kr + (size_t)kv * S_LEN * HDIM;
  float lsum = 0.f;
  const int nsteps = (qt + 1) * 2;

  for (int kt = 0; kt < nsteps; kt++) {
    const int j0 = kt * 64;
    __syncthreads();
#pragma unroll
    for (int r = 0; r < 4; r++) {          // stage K tile 64x128 (1024 16B chunks)
      int ci = r * 256 + tid;
      int row = ci >> 4, c = ci & 15;
      short8 kvv = *(const short8*)(Kb + (size_t)(j0 + row) * HDIM + c * 8);
      lds_write8(&Ks[row * KS_STRIDE + c * 8], kvv);
    }
    __syncthreads();

    floatx16 sacc[2];
#pragma unroll
    for (int jt = 0; jt < 2; jt++)
#pragma unroll
      for (int r = 0; r < 16; r++) sacc[jt][r] = 0.f;
#pragma unroll
    for (int kc = 0; kc < 8; kc++) {
      short8 ak[2];
#pragma unroll
      for (int jt = 0; jt < 2; jt++)
        ak[jt] = lds_read8(&Ks[(jt * 32 + l31) * KS_STRIDE + kc * 16 + hf * 8]);
#pragma unroll
      for (int jt = 0; jt < 2; jt++)
        sacc[jt] = __builtin_amdgcn_mfma_f32_32x32x16_bf16(ak[jt], fq[kc], sacc[jt], 0, 0, 0);
    }
    if (kt >= nsteps - 2) {   // boundary: causal mask j > i
#pragma unroll
      for (int jt = 0; jt < 2; jt++)
#pragma unroll
        for (int r = 0; r < 16; r++) {
          int j = j0 + jt * 32 + (r & 3) + 8 * (r >> 2) + 4 * hf;
          if (j > iCol) sacc[jt][r] = -3.0e38f;
        }
    }
#pragma unroll
    for (int jt = 0; jt < 2; jt++)
#pragma unroll
      for (int r = 0; r < 16; r++) lsum += exp2f(sacc[jt][r]);
  }
  lsum += __shfl_xor(lsum, 32);
  if (hf == 0) Lg[h * S_LEN + iCol] = log2f(lsum);
}

// ---------------- sweep B: P = exp2(S - L), colsums, O = P·V ----------------
// S orientation (cols j) -> colsum over i = 15 in-lane adds + 1 shuffle per 32 j.
// P -> A-op layout via wave-private LDS; V staged [d][j]; O^T accumulated, transposed
// through the (manual-arena) LDS once per block at the end.
__global__ __launch_bounds__(256, 2) void attn_pv_kernel(
    const short* __restrict__ Qr, const short* __restrict__ Kr,
    const short* __restrict__ Vt, const float* __restrict__ Lg,
    short* __restrict__ attn_out, float* __restrict__ part) {
  __shared__ __align__(16) short arena[AR_TOT];   // 52.5 KB single object
  short* Ks = &arena[AR_KS];                      // [j 64][d 128] stride 132
  short* Vs = &arena[AR_VS];                      // [d 128][j 64] stride 68
  float* cbuf = (float*)&arena[AR_CB];            // [2][4][64]

  const int bid = blockIdx.x;
  const int h = bid & 15;
  const int slot = bid >> 4;
  const int qt = (slot & 1) ? (slot >> 1) : (31 - (slot >> 1));
  const int kv = h >> 3;
  const int tid = threadIdx.x;
  const int lane = tid & 63;
  const int w = tid >> 6;
  const int l31 = lane & 31, hf = lane >> 5;
  const int i0 = qt * 128;
  const int iCol = i0 + w * 32 + l31;

  short8 fq[8];
#pragma unroll
  for (int kc = 0; kc < 8; kc++)
    fq[kc] = *(const short8*)(Qr + ((size_t)h * S_LEN + iCol) * HDIM + kc * 16 + hf * 8);

  float negL[16];
#pragma unroll
  for (int r = 0; r < 16; r++) {
    int i = i0 + w * 32 + (r & 3) + 8 * (r >> 2) + 4 * hf;
    negL[r] = -Lg[h * S_LEN + i];
  }

  floatx16 accO[4];
#pragma unroll
  for (int dt = 0; dt < 4; dt++)
#pragma unroll
    for (int r = 0; r < 16; r++) accO[dt][r] = 0.f;

  const short* Kb = Kr + (size_t)kv * S_LEN * HDIM;
  const short* Vb = Vt + (size_t)kv * HDIM * S_LEN;
  short* myP = &arena[AR_PS + w * 32 * PS_STRIDE];
  const int nsteps = (qt + 1) * 2;

  for (int kt = 0; kt < nsteps; kt++) {
    const int j0 = kt * 64;
    __syncthreads();
#pragma unroll
    for (int r = 0; r < 4; r++) {
      int ci = r * 256 + tid;
      int row = ci >> 4, c = ci & 15;          // K tile 64 x 128
      short8 kvv = *(const short8*)(Kb + (size_t)(j0 + row) * HDIM + c * 8);
      lds_write8(&Ks[row * KS_STRIDE + c * 8], kvv);
      int vr = ci >> 3, vc = ci & 7;           // V tile 128(d) x 64(j)
      short8 vv = *(const short8*)(Vb + (size_t)vr * S_LEN + j0 + vc * 8);
      lds_write8(&Vs[vr * VS_STRIDE + vc * 8], vv);
    }
    __syncthreads();
    // flush previous step's colsum (cbuf[(kt-1)&1] stable after the barrier)
    if (kt > 0 && tid < 64) {
      int pb = (kt - 1) & 1;
      float s = cbuf[pb * 256 + 0 * 64 + tid] + cbuf[pb * 256 + 1 * 64 + tid] +
                cbuf[pb * 256 + 2 * 64 + tid] + cbuf[pb * 256 + 3 * 64 + tid];
      part[((size_t)(h * 32 + qt)) * 4096 + (size_t)(kt - 1) * 64 + tid] = s;
    }

    floatx16 sacc[2];
#pragma unroll
    for (int jt = 0; jt < 2; jt++)
#pragma unroll
      for (int r = 0; r < 16; r++) sacc[jt][r] = negL[r];   // -L folded into C init
#pragma unroll
    for (int kc = 0; kc < 8; kc++) {
      short8 bk[2];
#pragma unroll
      for (int jt = 0; jt < 2; jt++)
        bk[jt] = lds_read8(&Ks[(jt * 32 + l31) * KS_STRIDE + kc * 16 + hf * 8]);
#pragma unroll
      for (int jt = 0; jt < 2; jt++)
        sacc[jt] = __builtin_amdgcn_mfma_f32_32x32x16_bf16(fq[kc], bk[jt], sacc[jt], 0, 0, 0);
    }

    const bool bnd = (kt >= nsteps - 2);
#pragma unroll
    for (int jt = 0; jt < 2; jt++) {
      float csum = 0.f;
#pragma unroll
      for (int r = 0; r < 16; r++) {
        float p = exp2f(sacc[jt][r]);
        if (bnd) {
          int j = j0 + jt * 32 + l31;
          int i = i0 + w * 32 + (r & 3) + 8 * (r >> 2) + 4 * hf;
          if (j > i) p = 0.f;
        }
        csum += p;
        int iloc = (r & 3) + 8 * (r >> 2) + 4 * hf;
        myP[iloc * PS_STRIDE + jt * 32 + l31] = f2bf(p);
      }
      csum += __shfl_xor(csum, 32);
      if (hf == 0) cbuf[(kt & 1) * 256 + w * 64 + jt * 32 + l31] = csum;
    }

    // PV: O^T[d][i] += V^T[d][j] · P^T[j][i]  (A = Vs rows d, B = P rows i)
#pragma unroll
    for (int kc2 = 0; kc2 < 4; kc2++) {
      short8 bp = lds_read8(&myP[l31 * PS_STRIDE + kc2 * 16 + hf * 8]);
#pragma unroll
      for (int dt = 0; dt < 4; dt++) {
        short8 av = lds_read8(&Vs[(dt * 32 + l31) * VS_STRIDE + kc2 * 16 + hf * 8]);
        accO[dt] = __builtin_amdgcn_mfma_f32_32x32x16_bf16(av, bp, accO[dt], 0, 0, 0);
      }
    }
  }

  __syncthreads();
  if (tid < 64) {   // flush last step's colsum (cbuf region is disjoint from Es span)
    int pb = (nsteps - 1) & 1;
    float s = cbuf[pb * 256 + 0 * 64 + tid] + cbuf[pb * 256 + 1 * 64 + tid] +
              cbuf[pb * 256 + 2 * 64 + tid] + cbuf[pb * 256 + 3 * 64 + tid];
    part[((size_t)(h * 32 + qt)) * 4096 + (size_t)(nsteps - 1) * 64 + tid] = s;
  }

  // epilogue: O^T (C-layout, col i = l31) -> LDS transpose -> coalesced bf16 stores.
  // Es = arena[0..16891], within Ks+Vs (dead), same single object -> well-defined.
  short* Es = &arena[0];   // per-wave area [i 32][d 128] at stride 132 shorts
#pragma unroll
  for (int dt = 0; dt < 4; dt++)
#pragma unroll
    for (int r = 0; r < 16; r++) {
      int d = dt * 32 + (r & 3) + 8 * (r >> 2) + 4 * hf;
      Es[w * 4224 + l31 * 132 + d] = f2bf(accO[dt][r]);
    }
  __syncthreads();
#pragma unroll
  for (int it = 0; it < 16; it++) {
    int idx = it * 256 + tid;            // 4096 b64 chunks: [a 4][row 32][c 32]
    int c = idx & 31, row = (idx >> 5) & 31, a = idx >> 10;
    uint2 v = *(const uint2*)(&Es[a * 4224 + row * 132 + c * 4]);
    *(uint2*)(attn_out + (size_t)(i0 + a * 32 + row) * HIDDEN + h * HDIM + c * 4) = v;
  }
}

// ---------------- colsum reduction: part -> acc_out (no atomics) ----------------
__global__ void reduce_acc(const float* __restrict__ part, float* __restrict__ acc) {
  int j = blockIdx.x * 256 + threadIdx.x;   // 0..8191
  int kvg = j >> 12, jj = j & 4095;
  float s = 0.f;
  for (int h = kvg * 8; h < kvg * 8 + 8; h++)
    for (int qt = jj >> 7; qt < 32; qt++)
      s += part[((size_t)(h * 32 + qt)) * 4096 + jj];
  acc[j] = s * 0.125f;
}

// ---------------- launch ----------------
extern "C" void kernel_launch(void* const* d_in, const int* in_sizes, int n_in,
                              void* d_out, int out_size, void* d_ws, size_t ws_size,
                              hipStream_t stream) {
  const float* hs = (const float*)d_in[0];
  const float* qw = (const float*)d_in[1];
  const float* qb = (const float*)d_in[2];
  const float* kw = (const float*)d_in[3];
  const float* kb = (const float*)d_in[4];
  const float* vw = (const float*)d_in[5];
  const float* vb = (const float*)d_in[6];
  const float* ow = (const float*)d_in[7];

  char* p = (char*)d_ws;
  auto alloc = [&](size_t bytes) { char* r = p; p += (bytes + 255) & ~(size_t)255; return r; };
  short* hs_b   = (short*)alloc((size_t)S_LEN * HIDDEN * 2);
  short* w_b    = (short*)alloc((size_t)2560 * HIDDEN * 2);
  short* ow_b   = (short*)alloc((size_t)HIDDEN * HIDDEN * 2);
  float* bias   = (float*)alloc(2560 * 4);
  short* qkv_t  = (short*)alloc((size_t)S_LEN * 2560 * 2);
  short* Qr     = (short*)alloc((size_t)NHEADS * S_LEN * HDIM * 2);
  short* Kr     = (short*)alloc((size_t)NKVH * S_LEN * HDIM * 2);
  short* Vt     = (short*)alloc((size_t)NKVH * HDIM * S_LEN * 2);
  short* attn_b = (short*)alloc((size_t)S_LEN * HIDDEN * 2);
  float* part   = (float*)alloc((size_t)NHEADS * 32 * 4096 * 4);
  float* Lg     = (float*)alloc((size_t)NHEADS * S_LEN * 4);

  float* out = (float*)d_out;
  float* acc_out = out + (size_t)S_LEN * HIDDEN;

  cast_kernel<<<4096, 256, 0, stream>>>(hs, qw, kw, vw, qb, kb, vb, ow, hs_b, w_b, ow_b, bias);
  gemm_bt<2560, true, true><<<dim3(20, 32), 256, 0, stream>>>(hs_b, w_b, bias, qkv_t, HIDDEN);
  rope_kernel<<<S_LEN, 256, 0, stream>>>(qkv_t, Qr, Kr, Vt);
  attn_l_kernel<<<512, 256, 0, stream>>>(Qr, Kr, Lg);
  attn_pv_kernel<<<512, 256, 0, stream>>>(Qr, Kr, Vt, Lg, attn_b, part);
  reduce_acc<<<32, 256, 0, stream>>>(part, acc_out);
  gemm_bt<2048, false, false><<<dim3(16, 32), 256, 0, stream>>>(attn_b, ow_b, nullptr, out, HIDDEN);
}

// Round 6
// 477.714 us; speedup vs baseline: 2.7640x; 1.1908x over previous
//
#include <hip/hip_runtime.h>
#include <hip/hip_bf16.h>
#include <cstdint>
#include <cstddef>

#define S_LEN 4096
#define HIDDEN 2048
#define NHEADS 16
#define NKVH 2
#define HDIM 128

typedef __attribute__((ext_vector_type(8))) short short8;
typedef __attribute__((ext_vector_type(4))) short short4v;
typedef __attribute__((ext_vector_type(4))) float floatx4;
typedef __attribute__((ext_vector_type(16))) float floatx16;

__device__ __forceinline__ short f2bf(float f) {
  uint32_t u = __builtin_bit_cast(uint32_t, f);
  uint32_t r = (u + 0x7fffu + ((u >> 16) & 1u)) >> 16;
  return (short)(uint16_t)r;
}
__device__ __forceinline__ float bf2f(short s) {
  uint32_t u = ((uint32_t)(uint16_t)s) << 16;
  return __builtin_bit_cast(float, u);
}
// XOR-swizzled element offset within a row of a row-major LDS tile; 16B chunks intact.
__device__ __forceinline__ int swz(int row, int ks, int mask) {
  int chunk = ks >> 3;
  return ((chunk ^ (row & mask)) << 3) | (ks & 7);
}
// 16B LDS read/write as 2x b64 (for odd-stride layouts that break b128 alignment)
__device__ __forceinline__ short8 lds_read8(const short* p) {
  short4v a = *(const short4v*)p;
  short4v b = *(const short4v*)(p + 4);
  short8 r;
  r[0] = a[0]; r[1] = a[1]; r[2] = a[2]; r[3] = a[3];
  r[4] = b[0]; r[5] = b[1]; r[6] = b[2]; r[7] = b[3];
  return r;
}
__device__ __forceinline__ void lds_write8(short* p, short8 v) {
  *(short4v*)p = (short4v){v[0], v[1], v[2], v[3]};
  *(short4v*)(p + 4) = (short4v){v[4], v[5], v[6], v[7]};
}

// Chunk decode: 48 slots per head, descending step-count order.
// mode 0 = direct (qt<16, full sweep), 1 = first-half partial (slab0, 32 steps),
// 2 = second-half partial (slab1).
__device__ __forceinline__ void decode_slot(int slot, int& qt, int& kb, int& cs, int& mode) {
  if (slot < 16) { qt = 16 + slot; kb = 0; cs = 32; mode = 1; }
  else {
    int r = (slot - 16) >> 1;
    if (!(slot & 1)) { qt = 15 - r; kb = 0;  cs = 2 * (qt + 1);      mode = 0; }
    else             { qt = 31 - r; kb = 32; cs = 2 * (qt + 1) - 32; mode = 2; }
  }
}

// ---------------- cast / pack kernel (float4 -> bf16x4) ----------------
__device__ __forceinline__ void cvt4(const float* __restrict__ src, short* __restrict__ dst, int qi) {
  float4 v = ((const float4*)src)[qi];
  short4v o = { f2bf(v.x), f2bf(v.y), f2bf(v.z), f2bf(v.w) };
  ((short4v*)dst)[qi] = o;
}
__global__ void cast_kernel(const float* __restrict__ hs, const float* __restrict__ qw,
                            const float* __restrict__ kw, const float* __restrict__ vw,
                            const float* __restrict__ qb, const float* __restrict__ kb,
                            const float* __restrict__ vb, const float* __restrict__ ow,
                            short* __restrict__ hs_b, short* __restrict__ w_b,
                            short* __restrict__ ow_b, float* __restrict__ bias) {
  const int HS_Q = S_LEN * HIDDEN / 4;
  const int QW_Q = NHEADS * HDIM * HIDDEN / 4;
  const int KW_Q = NKVH * HDIM * HIDDEN / 4;
  const int OW_Q = HIDDEN * HIDDEN / 4;
  const int TOTQ = HS_Q + QW_Q + 2 * KW_Q + OW_Q + 640;
  int idx = blockIdx.x * blockDim.x + threadIdx.x;
  int stride = gridDim.x * blockDim.x;
  for (int i = idx; i < TOTQ; i += stride) {
    int j = i;
    if (j < HS_Q) { cvt4(hs, hs_b, j); continue; }
    j -= HS_Q;
    if (j < QW_Q) { cvt4(qw, w_b, j); continue; }
    j -= QW_Q;
    if (j < KW_Q) { cvt4(kw, w_b + NHEADS * HDIM * HIDDEN, j); continue; }
    j -= KW_Q;
    if (j < KW_Q) { cvt4(vw, w_b + (NHEADS + NKVH) * HDIM * HIDDEN, j); continue; }
    j -= KW_Q;
    if (j < OW_Q) { cvt4(ow, ow_b, j); continue; }
    j -= OW_Q;
    if (j < 512) { ((float4*)bias)[j] = ((const float4*)qb)[j]; continue; }
    j -= 512;
    if (j < 64) { ((float4*)(bias + 2048))[j] = ((const float4*)kb)[j]; continue; }
    j -= 64;
    ((float4*)(bias + 2304))[j] = ((const float4*)vb)[j];
  }
}

// ---------------- GEMM: C[M][N] = A[M][K] @ B[N][K]^T (+bias) ----------------
template<int N_COLS, bool BIAS, bool OUT_BF16>
__global__ __launch_bounds__(256, 2) void gemm_bt(const short* __restrict__ A,
                                                  const short* __restrict__ B,
                                                  const float* __restrict__ bias,
                                                  void* __restrict__ Cout, int K) {
  __shared__ __align__(16) short As[128 * 64];
  __shared__ __align__(16) short Bs[128 * 64];
  const int tid = threadIdx.x;
  const int lane = tid & 63;
  const int w = tid >> 6;
  const int wr = w >> 1, wc = w & 1;
  const int m0 = blockIdx.y * 128;
  const int n0 = blockIdx.x * 128;
  const int l15 = lane & 15, q = lane >> 4;

  floatx4 acc[4][4];
#pragma unroll
  for (int i = 0; i < 4; i++)
#pragma unroll
    for (int j = 0; j < 4; j++) acc[i][j] = (floatx4){0.f, 0.f, 0.f, 0.f};

  for (int k0 = 0; k0 < K; k0 += 64) {
#pragma unroll
    for (int r = 0; r < 4; r++) {
      int ci = r * 256 + tid;
      int row = ci >> 3, cc = (ci & 7) << 3;
      short8 av = *(const short8*)(A + (size_t)(m0 + row) * K + k0 + cc);
      *(short8*)(&As[row * 64 + swz(row, cc, 7)]) = av;
      short8 bv = *(const short8*)(B + (size_t)(n0 + row) * K + k0 + cc);
      *(short8*)(&Bs[row * 64 + swz(row, cc, 7)]) = bv;
    }
    __syncthreads();
#pragma unroll
    for (int ko = 0; ko < 2; ko++) {
      short8 a[4], b[4];
#pragma unroll
      for (int i = 0; i < 4; i++) {
        int m = wr * 64 + i * 16 + l15;
        a[i] = *(const short8*)(&As[m * 64 + swz(m, ko * 32 + q * 8, 7)]);
      }
#pragma unroll
      for (int j = 0; j < 4; j++) {
        int n = wc * 64 + j * 16 + l15;
        b[j] = *(const short8*)(&Bs[n * 64 + swz(n, ko * 32 + q * 8, 7)]);
      }
#pragma unroll
      for (int i = 0; i < 4; i++)
#pragma unroll
        for (int j = 0; j < 4; j++)
          acc[i][j] = __builtin_amdgcn_mfma_f32_16x16x32_bf16(a[i], b[j], acc[i][j], 0, 0, 0);
    }
    __syncthreads();
  }
#pragma unroll
  for (int i = 0; i < 4; i++)
#pragma unroll
    for (int j = 0; j < 4; j++) {
      int n = n0 + wc * 64 + j * 16 + l15;
      float bv = 0.f;
      if (BIAS) bv = bias[n];
#pragma unroll
      for (int r = 0; r < 4; r++) {
        int m = m0 + wr * 64 + i * 16 + q * 4 + r;
        float v = acc[i][j][r] + bv;
        if (OUT_BF16) ((short*)Cout)[(size_t)m * N_COLS + n] = f2bf(v);
        else          ((float*)Cout)[(size_t)m * N_COLS + n] = v;
      }
    }
}

// ---------------- RoPE + scatter ----------------
__global__ void rope_kernel(const short* __restrict__ qkv, short* __restrict__ Qr,
                            short* __restrict__ Kr, short* __restrict__ Vt) {
  const int s = blockIdx.x;
  const int tid = threadIdx.x;
  const short* row = qkv + (size_t)s * 2560;
  const float QSCALE = 0.08838834764831845f * 1.4426950408889634f; // 1/sqrt(128)*log2(e)
  const float L2T_64 = 19.931568569324174f / 64.0f;                 // log2(1e6)/64
  for (int p = tid; p < 1152; p += 256) {
    int h = p >> 6;
    int d = p & 63;
    int base = h * 128;
    float x1 = bf2f(row[base + d]);
    float x2 = bf2f(row[base + d + 64]);
    float invf = exp2f(-(float)d * L2T_64);
    float ang = (float)s * invf;
    float sn, cs;
    sincosf(ang, &sn, &cs);
    float o1 = x1 * cs - x2 * sn;
    float o2 = x2 * cs + x1 * sn;
    if (h < 16) {
      size_t o = ((size_t)h * S_LEN + s) * HDIM;
      Qr[o + d] = f2bf(o1 * QSCALE);
      Qr[o + d + 64] = f2bf(o2 * QSCALE);
    } else {
      size_t o = ((size_t)(h - 16) * S_LEN + s) * HDIM;
      Kr[o + d] = f2bf(o1);
      Kr[o + d + 64] = f2bf(o2);
    }
  }
  for (int p = tid; p < 256; p += 256) {
    int kv = p >> 7, d = p & 127;
    Vt[((size_t)kv * HDIM + d) * S_LEN + s] = row[2304 + p];
  }
}

// Shared helpers for the 32x32x16 attention kernels.
// C/D layout (verified): col(n) = lane&31, row(m) = (reg&3) + 8*(reg>>2) + 4*(lane>>5).
// A/B operand: m/n = lane&31, k = (lane>>5)*8 + idx.
#define KS_STRIDE 132   // odd dword stride -> 2-way max on frag reads, 2xb64 access
#define VS_STRIDE 68
#define PS_STRIDE 68

// Manual LDS arena offsets for attn_pv (shorts). Single object => the epilogue
// overlay (Es spans Ks+Vs) is well-defined, provably disjoint from Ps/cbuf.
#define AR_KS   0                    // 64*132  = 8448 shorts
#define AR_VS   8448                 // 128*68  = 8704 shorts
#define AR_PS   17152                // 4*32*68 = 8704 shorts
#define AR_CB   25856                // cbuf: 2*4*64 floats = 1024 shorts
#define AR_TOT  26880                // 53760 bytes; 3 blocks/CU (3*53760 <= 160KB)

// ---------------- sweep A: partial row sums -> atomicAdd Lsum ----------------
// S^T = K·Q^T chunked over keys; fixed-base partial sums are exactly additive.
__global__ __launch_bounds__(256, 4) void attn_l_kernel(
    const short* __restrict__ Qr, const short* __restrict__ Kr,
    float* __restrict__ Lsum) {
  __shared__ __align__(16) short Ks[64 * KS_STRIDE];   // 16.5 KB [j][d]

  const int bid = blockIdx.x;
  const int h = bid & 15;
  int qt, kb, cs, mode;
  decode_slot(bid >> 4, qt, kb, cs, mode);
  const int kv = h >> 3;
  const int tid = threadIdx.x;
  const int lane = tid & 63;
  const int w = tid >> 6;
  const int l31 = lane & 31, hf = lane >> 5;
  const int i0 = qt * 128;
  const int iCol = i0 + w * 32 + l31;   // this lane's query column
  const int nst = 2 * (qt + 1);

  short8 fq[8];
#pragma unroll
  for (int kc = 0; kc < 8; kc++)
    fq[kc] = *(const short8*)(Qr + ((size_t)h * S_LEN + iCol) * HDIM + kc * 16 + hf * 8);

  const short* Kb = Kr + (size_t)kv * S_LEN * HDIM;
  float lsum = 0.f;

  for (int kt = 0; kt < cs; kt++) {
    const int gkt = kb + kt;
    const int j0 = gkt * 64;
    __syncthreads();
#pragma unroll
    for (int r = 0; r < 4; r++) {          // stage K tile 64x128 (1024 16B chunks)
      int ci = r * 256 + tid;
      int row = ci >> 4, c = ci & 15;
      short8 kvv = *(const short8*)(Kb + (size_t)(j0 + row) * HDIM + c * 8);
      lds_write8(&Ks[row * KS_STRIDE + c * 8], kvv);
    }
    __syncthreads();

    floatx16 sacc[2];
#pragma unroll
    for (int jt = 0; jt < 2; jt++)
#pragma unroll
      for (int r = 0; r < 16; r++) sacc[jt][r] = 0.f;
#pragma unroll
    for (int kc = 0; kc < 8; kc++) {
      short8 ak[2];
#pragma unroll
      for (int jt = 0; jt < 2; jt++)
        ak[jt] = lds_read8(&Ks[(jt * 32 + l31) * KS_STRIDE + kc * 16 + hf * 8]);
#pragma unroll
      for (int jt = 0; jt < 2; jt++)
        sacc[jt] = __builtin_amdgcn_mfma_f32_32x32x16_bf16(ak[jt], fq[kc], sacc[jt], 0, 0, 0);
    }
    if (gkt >= nst - 2) {   // boundary: causal mask j > i
#pragma unroll
      for (int jt = 0; jt < 2; jt++)
#pragma unroll
        for (int r = 0; r < 16; r++) {
          int j = j0 + jt * 32 + (r & 3) + 8 * (r >> 2) + 4 * hf;
          if (j > iCol) sacc[jt][r] = -3.0e38f;
        }
    }
#pragma unroll
    for (int jt = 0; jt < 2; jt++)
#pragma unroll
      for (int r = 0; r < 16; r++) lsum += exp2f(sacc[jt][r]);
  }
  lsum += __shfl_xor(lsum, 32);
  if (hf == 0) atomicAdd(&Lsum[h * S_LEN + iCol], lsum);
}

// ---------------- sweep B: P = exp2(S - L), colsums, O = P·V (chunked) ----------------
__global__ __launch_bounds__(256, 2) void attn_pv_kernel(
    const short* __restrict__ Qr, const short* __restrict__ Kr,
    const short* __restrict__ Vt, const float* __restrict__ Lsum,
    short* __restrict__ attn_out, short* __restrict__ slab0,
    short* __restrict__ slab1, float* __restrict__ part) {
  __shared__ __align__(16) short arena[AR_TOT];   // 52.5 KB single object
  short* Ks = &arena[AR_KS];                      // [j 64][d 128] stride 132
  short* Vs = &arena[AR_VS];                      // [d 128][j 64] stride 68
  float* cbuf = (float*)&arena[AR_CB];            // [2][4][64]

  const int bid = blockIdx.x;
  const int h = bid & 15;
  int qt, kb, cs, mode;
  decode_slot(bid >> 4, qt, kb, cs, mode);
  const int kv = h >> 3;
  const int tid = threadIdx.x;
  const int lane = tid & 63;
  const int w = tid >> 6;
  const int l31 = lane & 31, hf = lane >> 5;
  const int i0 = qt * 128;
  const int iCol = i0 + w * 32 + l31;
  const int nst = 2 * (qt + 1);

  short8 fq[8];
#pragma unroll
  for (int kc = 0; kc < 8; kc++)
    fq[kc] = *(const short8*)(Qr + ((size_t)h * S_LEN + iCol) * HDIM + kc * 16 + hf * 8);

  float negL[16];
#pragma unroll
  for (int r = 0; r < 16; r++) {
    int i = i0 + w * 32 + (r & 3) + 8 * (r >> 2) + 4 * hf;
    negL[r] = -log2f(Lsum[h * S_LEN + i]);
  }

  floatx16 accO[4];
#pragma unroll
  for (int dt = 0; dt < 4; dt++)
#pragma unroll
    for (int r = 0; r < 16; r++) accO[dt][r] = 0.f;

  const short* Kb = Kr + (size_t)kv * S_LEN * HDIM;
  const short* Vb = Vt + (size_t)kv * HDIM * S_LEN;
  short* myP = &arena[AR_PS + w * 32 * PS_STRIDE];

  for (int kt = 0; kt < cs; kt++) {
    const int gkt = kb + kt;
    const int j0 = gkt * 64;
    __syncthreads();
#pragma unroll
    for (int r = 0; r < 4; r++) {
      int ci = r * 256 + tid;
      int row = ci >> 4, c = ci & 15;          // K tile 64 x 128
      short8 kvv = *(const short8*)(Kb + (size_t)(j0 + row) * HDIM + c * 8);
      lds_write8(&Ks[row * KS_STRIDE + c * 8], kvv);
      int vr = ci >> 3, vc = ci & 7;           // V tile 128(d) x 64(j)
      short8 vv = *(const short8*)(Vb + (size_t)vr * S_LEN + j0 + vc * 8);
      lds_write8(&Vs[vr * VS_STRIDE + vc * 8], vv);
    }
    __syncthreads();
    // flush previous step's colsum (cbuf[(gkt-1)&1] stable after the barrier)
    if (kt > 0 && tid < 64) {
      int pb = (gkt - 1) & 1;
      float s = cbuf[pb * 256 + 0 * 64 + tid] + cbuf[pb * 256 + 1 * 64 + tid] +
                cbuf[pb * 256 + 2 * 64 + tid] + cbuf[pb * 256 + 3 * 64 + tid];
      part[((size_t)(h * 32 + qt)) * 4096 + (size_t)(gkt - 1) * 64 + tid] = s;
    }

    floatx16 sacc[2];
#pragma unroll
    for (int jt = 0; jt < 2; jt++)
#pragma unroll
      for (int r = 0; r < 16; r++) sacc[jt][r] = negL[r];   // -L folded into C init
#pragma unroll
    for (int kc = 0; kc < 8; kc++) {
      short8 bk[2];
#pragma unroll
      for (int jt = 0; jt < 2; jt++)
        bk[jt] = lds_read8(&Ks[(jt * 32 + l31) * KS_STRIDE + kc * 16 + hf * 8]);
#pragma unroll
      for (int jt = 0; jt < 2; jt++)
        sacc[jt] = __builtin_amdgcn_mfma_f32_32x32x16_bf16(fq[kc], bk[jt], sacc[jt], 0, 0, 0);
    }

    const bool bnd = (gkt >= nst - 2);
#pragma unroll
    for (int jt = 0; jt < 2; jt++) {
      float csum = 0.f;
#pragma unroll
      for (int r = 0; r < 16; r++) {
        float p = exp2f(sacc[jt][r]);
        if (bnd) {
          int j = j0 + jt * 32 + l31;
          int i = i0 + w * 32 + (r & 3) + 8 * (r >> 2) + 4 * hf;
          if (j > i) p = 0.f;
        }
        csum += p;
        int iloc = (r & 3) + 8 * (r >> 2) + 4 * hf;
        myP[iloc * PS_STRIDE + jt * 32 + l31] = f2bf(p);
      }
      csum += __shfl_xor(csum, 32);
      if (hf == 0) cbuf[(gkt & 1) * 256 + w * 64 + jt * 32 + l31] = csum;
    }

    // PV: O^T[d][i] += V^T[d][j] · P^T[j][i]  (A = Vs rows d, B = P rows i)
#pragma unroll
    for (int kc2 = 0; kc2 < 4; kc2++) {
      short8 bp = lds_read8(&myP[l31 * PS_STRIDE + kc2 * 16 + hf * 8]);
#pragma unroll
      for (int dt = 0; dt < 4; dt++) {
        short8 av = lds_read8(&Vs[(dt * 32 + l31) * VS_STRIDE + kc2 * 16 + hf * 8]);
        accO[dt] = __builtin_amdgcn_mfma_f32_32x32x16_bf16(av, bp, accO[dt], 0, 0, 0);
      }
    }
  }

  __syncthreads();
  if (tid < 64) {   // flush last step's colsum
    int pb = (kb + cs - 1) & 1;
    float s = cbuf[pb * 256 + 0 * 64 + tid] + cbuf[pb * 256 + 1 * 64 + tid] +
              cbuf[pb * 256 + 2 * 64 + tid] + cbuf[pb * 256 + 3 * 64 + tid];
    part[((size_t)(h * 32 + qt)) * 4096 + (size_t)(kb + cs - 1) * 64 + tid] = s;
  }

  // epilogue: O^T (C-layout, col i = l31) -> LDS transpose -> coalesced bf16 stores.
  // Es = arena[0..16891], within Ks+Vs (dead), same single object -> well-defined.
  short* obase = (mode == 0) ? attn_out : (mode == 1 ? slab0 : slab1);
  short* Es = &arena[0];   // per-wave area [i 32][d 128] at stride 132 shorts
#pragma unroll
  for (int dt = 0; dt < 4; dt++)
#pragma unroll
    for (int r = 0; r < 16; r++) {
      int d = dt * 32 + (r & 3) + 8 * (r >> 2) + 4 * hf;
      Es[w * 4224 + l31 * 132 + d] = f2bf(accO[dt][r]);
    }
  __syncthreads();
#pragma unroll
  for (int it = 0; it < 16; it++) {
    int idx = it * 256 + tid;            // 4096 b64 chunks: [a 4][row 32][c 32]
    int c = idx & 31, row = (idx >> 5) & 31, a = idx >> 10;
    uint2 v = *(const uint2*)(&Es[a * 4224 + row * 132 + c * 4]);
    *(uint2*)(obase + (size_t)(i0 + a * 32 + row) * HIDDEN + h * HDIM + c * 4) = v;
  }
}

// ---------------- merge partial O slabs (rows 2048..4095) ----------------
__global__ void merge_o(const short* __restrict__ a, const short* __restrict__ b,
                        short* __restrict__ o) {
  int idx = blockIdx.x * 256 + threadIdx.x;   // 524288 short8 chunks
  size_t e = (size_t)2048 * HIDDEN + (size_t)idx * 8;
  short8 va = *(const short8*)(a + e);
  short8 vb = *(const short8*)(b + e);
  short8 vo;
#pragma unroll
  for (int k = 0; k < 8; k++) vo[k] = f2bf(bf2f(va[k]) + bf2f(vb[k]));
  *(short8*)(o + e) = vo;
}

// ---------------- colsum reduction: part -> acc_out (no atomics) ----------------
__global__ void reduce_acc(const float* __restrict__ part, float* __restrict__ acc) {
  int j = blockIdx.x * 256 + threadIdx.x;   // 0..8191
  int kvg = j >> 12, jj = j & 4095;
  float s = 0.f;
  for (int h = kvg * 8; h < kvg * 8 + 8; h++)
    for (int qt = jj >> 7; qt < 32; qt++)
      s += part[((size_t)(h * 32 + qt)) * 4096 + jj];
  acc[j] = s * 0.125f;
}

// ---------------- launch ----------------
extern "C" void kernel_launch(void* const* d_in, const int* in_sizes, int n_in,
                              void* d_out, int out_size, void* d_ws, size_t ws_size,
                              hipStream_t stream) {
  const float* hs = (const float*)d_in[0];
  const float* qw = (const float*)d_in[1];
  const float* qb = (const float*)d_in[2];
  const float* kw = (const float*)d_in[3];
  const float* kb = (const float*)d_in[4];
  const float* vw = (const float*)d_in[5];
  const float* vb = (const float*)d_in[6];
  const float* ow = (const float*)d_in[7];

  char* p = (char*)d_ws;
  auto alloc = [&](size_t bytes) { char* r = p; p += (bytes + 255) & ~(size_t)255; return r; };
  short* hs_b   = (short*)alloc((size_t)S_LEN * HIDDEN * 2);
  short* w_b    = (short*)alloc((size_t)2560 * HIDDEN * 2);
  short* ow_b   = (short*)alloc((size_t)HIDDEN * HIDDEN * 2);
  float* bias   = (float*)alloc(2560 * 4);
  short* qkv_t  = (short*)alloc((size_t)S_LEN * 2560 * 2);
  short* Qr     = (short*)alloc((size_t)NHEADS * S_LEN * HDIM * 2);
  short* Kr     = (short*)alloc((size_t)NKVH * S_LEN * HDIM * 2);
  short* Vt     = (short*)alloc((size_t)NKVH * HDIM * S_LEN * 2);
  short* attn_b = (short*)alloc((size_t)S_LEN * HIDDEN * 2);
  float* part   = (float*)alloc((size_t)NHEADS * 32 * 4096 * 4);
  float* Lsum   = (float*)alloc((size_t)NHEADS * S_LEN * 4);
  short* slab0  = (short*)alloc((size_t)S_LEN * HIDDEN * 2);
  short* slab1  = (short*)alloc((size_t)S_LEN * HIDDEN * 2);

  float* out = (float*)d_out;
  float* acc_out = out + (size_t)S_LEN * HIDDEN;

  hipMemsetAsync(Lsum, 0, (size_t)NHEADS * S_LEN * 4, stream);
  cast_kernel<<<4096, 256, 0, stream>>>(hs, qw, kw, vw, qb, kb, vb, ow, hs_b, w_b, ow_b, bias);
  gemm_bt<2560, true, true><<<dim3(20, 32), 256, 0, stream>>>(hs_b, w_b, bias, qkv_t, HIDDEN);
  rope_kernel<<<S_LEN, 256, 0, stream>>>(qkv_t, Qr, Kr, Vt);
  attn_l_kernel<<<768, 256, 0, stream>>>(Qr, Kr, Lsum);
  attn_pv_kernel<<<768, 256, 0, stream>>>(Qr, Kr, Vt, Lsum, attn_b, slab0, slab1, part);
  merge_o<<<2048, 256, 0, stream>>>(slab0, slab1, attn_b);
  reduce_acc<<<32, 256, 0, stream>>>(part, acc_out);
  gemm_bt<2048, false, false><<<dim3(16, 32), 256, 0, stream>>>(attn_b, ow_b, nullptr, out, HIDDEN);
}